// Round 1
// baseline (113235.425 us; speedup 1.0000x reference)
//
#include <hip/hip_runtime.h>
#include <hip/hip_fp16.h>

typedef unsigned int u32;

#define BATCH 256
#define TSTEPS 1024
#define HDIM 256
#define ODIM 32

// ---------------- workspace layout (bytes) ----------------
#define OFF_MREG   0u          // u32 [3][256][128]  : half2-packed rows of M_r, M_z, M_hn
#define OFF_MXN    393216u     // u32 [128][256]     : M_xn transposed-packed: [pair p][unit j]
#define OFF_WO     524288u     // u32 [128][32]      : W_out transposed-packed: [pair p][o]
#define OFF_CVEC   540672u     // f32 [256][3][256]  : per-batch constants (steady state, t>=1)
#define OFF_CVEC0  1327104u    // f32 [256][3][256]  : per-batch constants for t==0 (uses init_y)

static __device__ __forceinline__ u32 packh2(float a, float b) {
  __half2 h = __floats2half2_rn(a, b);
  return *reinterpret_cast<u32*>(&h);
}
static __device__ __forceinline__ float2 up2(u32 u) {
  __half2 h = *reinterpret_cast<__half2*>(&u);
  return __half22float2(h);
}

// ---------------------------------------------------------------------------
// K1: build folded h-matrices in f16.
//   M_r[j][k]  = W_hh[j][k]       + sum_o W_ih[j][32+o]     * W_out[o][k]
//   M_z[j][k]  = W_hh[256+j][k]   + sum_o W_ih[256+j][32+o] * W_out[o][k]
//   M_hn[j][k] = W_hh[512+j][k]
//   M_xn[j][k] =                    sum_o W_ih[512+j][32+o] * W_out[o][k]
// grid 128 (k-pair p), block 256 (unit j)
// ---------------------------------------------------------------------------
__global__ void k_fold(const float* __restrict__ W_ih, const float* __restrict__ W_hh,
                       const float* __restrict__ W_out,
                       u32* __restrict__ Mreg, u32* __restrict__ MxnT2, u32* __restrict__ WoT2) {
  const int p = blockIdx.x;        // 0..127
  const int j = threadIdx.x;       // 0..255
  const int k0 = 2 * p, k1 = 2 * p + 1;

  float fr0 = 0.f, fr1 = 0.f, fz0 = 0.f, fz1 = 0.f, fn0 = 0.f, fn1 = 0.f;
#pragma unroll 8
  for (int o = 0; o < 32; ++o) {
    const float w0 = W_out[o * HDIM + k0];
    const float w1 = W_out[o * HDIM + k1];
    const float ar = W_ih[(j)       * 96 + 32 + o];
    const float az = W_ih[(256 + j) * 96 + 32 + o];
    const float an = W_ih[(512 + j) * 96 + 32 + o];
    fr0 = fmaf(ar, w0, fr0); fr1 = fmaf(ar, w1, fr1);
    fz0 = fmaf(az, w0, fz0); fz1 = fmaf(az, w1, fz1);
    fn0 = fmaf(an, w0, fn0); fn1 = fmaf(an, w1, fn1);
  }
  const float mr0 = W_hh[(j)       * HDIM + k0] + fr0;
  const float mr1 = W_hh[(j)       * HDIM + k1] + fr1;
  const float mz0 = W_hh[(256 + j) * HDIM + k0] + fz0;
  const float mz1 = W_hh[(256 + j) * HDIM + k1] + fz1;
  const float mh0 = W_hh[(512 + j) * HDIM + k0];
  const float mh1 = W_hh[(512 + j) * HDIM + k1];

  Mreg[(0 * 256 + j) * 128 + p] = packh2(mr0, mr1);
  Mreg[(1 * 256 + j) * 128 + p] = packh2(mz0, mz1);
  Mreg[(2 * 256 + j) * 128 + p] = packh2(mh0, mh1);
  MxnT2[p * 256 + j] = packh2(fn0, fn1);
  if (j < ODIM) WoT2[p * ODIM + j] = packh2(W_out[j * HDIM + k0], W_out[j * HDIM + k1]);
}

// ---------------------------------------------------------------------------
// K2: per-batch constant vectors.
//   q=0 (r):  b_ih[j]     + b_hh[j]     + W_ihz_r.z_b + W_ihy_r.(b_out | init_y)
//   q=1 (z):  b_ih[256+j] + b_hh[256+j] + ...
//   q=2 (xn): b_ih[512+j]               + ...          (b_hh_n stays separate)
// grid 256 (batch b), block 256 (unit j)
// ---------------------------------------------------------------------------
__global__ void k_cvec(const float* __restrict__ W_ih, const float* __restrict__ b_ih,
                       const float* __restrict__ b_hh, const float* __restrict__ b_out,
                       const float* __restrict__ z_dyn, const float* __restrict__ init_y,
                       float* __restrict__ cvec, float* __restrict__ cvec0) {
  const int b = blockIdx.x, j = threadIdx.x;
  __shared__ float zs[32], bo[32], y0[32];
  if (j < 32) {
    zs[j] = z_dyn[b * 32 + j];
    bo[j] = b_out[j];
    y0[j] = init_y[b * 32 + j];
  }
  __syncthreads();
#pragma unroll
  for (int q = 0; q < 3; ++q) {
    const int g = q * 256 + j;
    const float base = b_ih[g] + ((q < 2) ? b_hh[g] : 0.f);
    float zd = 0.f, yd = 0.f, y0d = 0.f;
#pragma unroll 8
    for (int u = 0; u < 32; ++u) {
      const float wz = W_ih[g * 96 + 64 + u];
      const float wy = W_ih[g * 96 + 32 + u];
      zd  = fmaf(wz, zs[u], zd);
      yd  = fmaf(wy, bo[u], yd);
      y0d = fmaf(wy, y0[u], y0d);
    }
    cvec [(b * 3 + q) * 256 + j] = base + zd + yd;
    cvec0[(b * 3 + q) * 256 + j] = base + zd + y0d;
  }
}

// ---------------------------------------------------------------------------
// Main persistent GRU kernel. grid 256 (batch), block 256 (hidden unit).
// Thread j owns gate rows {j, 256+j, 512+j}. Weights: M_r/M_z/M_hn in VGPRs
// (half2-packed), M_xn + W_out in LDS (lane-addressed, conflict-free), all
// activations fp32.
// LDS: mxn 131072 | wo 16384 | h 1024 | xobs 2*128 | ypart 1024  = 149760 B
// ---------------------------------------------------------------------------
#define SM_MXN 0
#define SM_WO  131072
#define SM_H   147456
#define SM_X   148480
#define SM_YP  148736
#define SM_BYTES 149760

__global__ __launch_bounds__(256, 1) void k_gru(
    const float* __restrict__ obs, const float* __restrict__ W_ih,
    const float* __restrict__ b_hh, const float* __restrict__ b_out,
    const u32* __restrict__ Mreg, const u32* __restrict__ MxnT2g,
    const u32* __restrict__ WoT2g, const float* __restrict__ cvec,
    const float* __restrict__ cvec0, float* __restrict__ out) {
  extern __shared__ char smem[];
  u32*   mxn_s = reinterpret_cast<u32*>(smem + SM_MXN);   // [128][256]
  u32*   wo_s  = reinterpret_cast<u32*>(smem + SM_WO);    // [128][32]
  float* h_s   = reinterpret_cast<float*>(smem + SM_H);   // [256]
  float* x_s   = reinterpret_cast<float*>(smem + SM_X);   // [2][32]
  float* yp_s  = reinterpret_cast<float*>(smem + SM_YP);  // [8][32]

  const int b = blockIdx.x;
  const int j = threadIdx.x;

  // ---- stage M_xn and W_out into LDS (coalesced uint4) ----
  {
    const uint4* src = reinterpret_cast<const uint4*>(MxnT2g);
    uint4* dst = reinterpret_cast<uint4*>(mxn_s);
#pragma unroll
    for (int i = 0; i < 32; ++i) dst[j + 256 * i] = src[j + 256 * i];
    const uint4* s2 = reinterpret_cast<const uint4*>(WoT2g);
    uint4* d2 = reinterpret_cast<uint4*>(wo_s);
#pragma unroll
    for (int i = 0; i < 4; ++i) d2[j + 256 * i] = s2[j + 256 * i];
  }

  // ---- per-thread weight registers ----
  u32 mr[128], mz[128], mhn[128];
  {
    const uint4* r0 = reinterpret_cast<const uint4*>(Mreg + (0 * 256 + j) * 128);
    const uint4* r1 = reinterpret_cast<const uint4*>(Mreg + (1 * 256 + j) * 128);
    const uint4* r2 = reinterpret_cast<const uint4*>(Mreg + (2 * 256 + j) * 128);
#pragma unroll
    for (int i = 0; i < 32; ++i) {
      uint4 a = r0[i]; mr[4 * i] = a.x; mr[4 * i + 1] = a.y; mr[4 * i + 2] = a.z; mr[4 * i + 3] = a.w;
      uint4 c = r1[i]; mz[4 * i] = c.x; mz[4 * i + 1] = c.y; mz[4 * i + 2] = c.z; mz[4 * i + 3] = c.w;
      uint4 d = r2[i]; mhn[4 * i] = d.x; mhn[4 * i + 1] = d.y; mhn[4 * i + 2] = d.z; mhn[4 * i + 3] = d.w;
    }
  }
  // obs-weight rows (f16-packed from fp32 W_ih), 16 regs each
  u32 owr[16], owz[16], own[16];
#pragma unroll
  for (int i = 0; i < 16; ++i) {
    owr[i] = packh2(W_ih[(j)       * 96 + 2 * i], W_ih[(j)       * 96 + 2 * i + 1]);
    owz[i] = packh2(W_ih[(256 + j) * 96 + 2 * i], W_ih[(256 + j) * 96 + 2 * i + 1]);
    own[i] = packh2(W_ih[(512 + j) * 96 + 2 * i], W_ih[(512 + j) * 96 + 2 * i + 1]);
  }

  const float c_r1 = cvec [(b * 3 + 0) * 256 + j];
  const float c_z1 = cvec [(b * 3 + 1) * 256 + j];
  const float c_n1 = cvec [(b * 3 + 2) * 256 + j];
  const float c_r0 = cvec0[(b * 3 + 0) * 256 + j];
  const float c_z0 = cvec0[(b * 3 + 1) * 256 + j];
  const float c_n0 = cvec0[(b * 3 + 2) * 256 + j];
  const float chn  = b_hh[512 + j];
  const float bo   = (j < ODIM) ? b_out[j] : 0.f;

  float hreg = 0.f;
  h_s[j] = 0.f;
  const float* obs_b = obs + (size_t)b * TSTEPS * 32;
  float* out_b = out + (size_t)b * TSTEPS * 32;
  if (j < 32) x_s[j] = obs_b[j];  // xobs buffer 0 = obs[t=0]
  __syncthreads();

  for (int t = 0; t < TSTEPS; ++t) {
    const int cur = t & 1;
    // prefetch next obs row early (hidden under the h-dot)
    float pf = 0.f;
    const int tn = (t < TSTEPS - 1) ? t + 1 : t;
    if (j >= 32 && j < 64) pf = obs_b[tn * 32 + (j - 32)];

    const float cr  = t ? c_r1 : c_r0;
    const float cz  = t ? c_z1 : c_z0;
    const float cxn = t ? c_n1 : c_n0;

    float aR = 0.f, aZ = 0.f, aXN = 0.f, aHN = 0.f;
#pragma unroll
    for (int q = 0; q < 64; ++q) {
      const float4 hv = *reinterpret_cast<const float4*>(&h_s[4 * q]);  // uniform → broadcast
      const u32 xa = mxn_s[(2 * q) * 256 + j];      // bank = j%32, conflict-free
      const u32 xb = mxn_s[(2 * q + 1) * 256 + j];
      float2 w;
      w = up2(mr[2 * q]);      aR = fmaf(w.x, hv.x, aR);  aR = fmaf(w.y, hv.y, aR);
      w = up2(mr[2 * q + 1]);  aR = fmaf(w.x, hv.z, aR);  aR = fmaf(w.y, hv.w, aR);
      w = up2(mz[2 * q]);      aZ = fmaf(w.x, hv.x, aZ);  aZ = fmaf(w.y, hv.y, aZ);
      w = up2(mz[2 * q + 1]);  aZ = fmaf(w.x, hv.z, aZ);  aZ = fmaf(w.y, hv.w, aZ);
      w = up2(mhn[2 * q]);     aHN = fmaf(w.x, hv.x, aHN); aHN = fmaf(w.y, hv.y, aHN);
      w = up2(mhn[2 * q + 1]); aHN = fmaf(w.x, hv.z, aHN); aHN = fmaf(w.y, hv.w, aHN);
      w = up2(xa);             aXN = fmaf(w.x, hv.x, aXN); aXN = fmaf(w.y, hv.y, aXN);
      w = up2(xb);             aXN = fmaf(w.x, hv.z, aXN); aXN = fmaf(w.y, hv.w, aXN);
    }
#pragma unroll
    for (int u = 0; u < 8; ++u) {
      const float4 xv = *reinterpret_cast<const float4*>(&x_s[cur * 32 + 4 * u]);
      float2 w;
      w = up2(owr[2 * u]);     aR = fmaf(w.x, xv.x, aR);  aR = fmaf(w.y, xv.y, aR);
      w = up2(owr[2 * u + 1]); aR = fmaf(w.x, xv.z, aR);  aR = fmaf(w.y, xv.w, aR);
      w = up2(owz[2 * u]);     aZ = fmaf(w.x, xv.x, aZ);  aZ = fmaf(w.y, xv.y, aZ);
      w = up2(owz[2 * u + 1]); aZ = fmaf(w.x, xv.z, aZ);  aZ = fmaf(w.y, xv.w, aZ);
      w = up2(own[2 * u]);     aXN = fmaf(w.x, xv.x, aXN); aXN = fmaf(w.y, xv.y, aXN);
      w = up2(own[2 * u + 1]); aXN = fmaf(w.x, xv.z, aXN); aXN = fmaf(w.y, xv.w, aXN);
    }

    const float r  = 1.f / (1.f + __expf(-(cr + aR)));
    const float zg = 1.f / (1.f + __expf(-(cz + aZ)));
    const float pn = cxn + aXN + r * (chn + aHN);
    const float n  = 1.f - 2.f / (1.f + __expf(2.f * pn));  // tanh(pn)
    const float hnew = fmaf(zg, hreg - n, n);               // (1-z)*n + z*h
    hreg = hnew;

    __syncthreads();                 // everyone done reading h_s / x_s[1-cur]
    h_s[j] = hnew;
    if (j >= 32 && j < 64) x_s[(1 - cur) * 32 + (j - 32)] = pf;
    __syncthreads();                 // new h visible

    // ---- y = W_out @ h + b_out (side output, off the recurrence path) ----
    {
      const int o = j & 31, kc = j >> 5, kb = kc * 32;
      float yp = 0.f;
#pragma unroll
      for (int kk = 0; kk < 32; kk += 4) {
        const float4 hv = *reinterpret_cast<const float4*>(&h_s[kb + kk]);
        const u32 w0 = wo_s[((kb + kk) >> 1) * 32 + o];
        const u32 w1 = wo_s[(((kb + kk) >> 1) + 1) * 32 + o];
        const float2 a = up2(w0), c = up2(w1);
        yp = fmaf(a.x, hv.x, yp); yp = fmaf(a.y, hv.y, yp);
        yp = fmaf(c.x, hv.z, yp); yp = fmaf(c.y, hv.w, yp);
      }
      yp_s[kc * 32 + o] = yp;
    }
    __syncthreads();
    if (j < ODIM) {
      float y = bo;
#pragma unroll
      for (int c = 0; c < 8; ++c) y += yp_s[c * 32 + j];
      out_b[t * 32 + j] = y;
    }
  }
}

// ---------------------------------------------------------------------------
extern "C" void kernel_launch(void* const* d_in, const int* in_sizes, int n_in,
                              void* d_out, int out_size, void* d_ws, size_t ws_size,
                              hipStream_t stream) {
  (void)in_sizes; (void)n_in; (void)out_size; (void)ws_size;
  const float* init_y  = (const float*)d_in[0];
  const float* obs_seq = (const float*)d_in[1];
  const float* z_dyn   = (const float*)d_in[2];
  const float* W_ih    = (const float*)d_in[3];
  const float* W_hh    = (const float*)d_in[4];
  const float* b_ih    = (const float*)d_in[5];
  const float* b_hh    = (const float*)d_in[6];
  const float* W_out   = (const float*)d_in[7];
  const float* b_out   = (const float*)d_in[8];
  float* out = (float*)d_out;

  char* ws = (char*)d_ws;
  u32*   Mreg  = (u32*)(ws + OFF_MREG);
  u32*   MxnT2 = (u32*)(ws + OFF_MXN);
  u32*   WoT2  = (u32*)(ws + OFF_WO);
  float* cvec  = (float*)(ws + OFF_CVEC);
  float* cvec0 = (float*)(ws + OFF_CVEC0);

  hipFuncSetAttribute((const void*)k_gru,
                      hipFuncAttributeMaxDynamicSharedMemorySize, SM_BYTES);

  k_fold<<<128, 256, 0, stream>>>(W_ih, W_hh, W_out, Mreg, MxnT2, WoT2);
  k_cvec<<<256, 256, 0, stream>>>(W_ih, b_ih, b_hh, b_out, z_dyn, init_y, cvec, cvec0);
  k_gru<<<BATCH, 256, SM_BYTES, stream>>>(obs_seq, W_ih, b_hh, b_out,
                                          Mreg, MxnT2, WoT2, cvec, cvec0, out);
}

// Round 2
// 65055.646 us; speedup vs baseline: 1.7406x; 1.7406x over previous
//
#include <hip/hip_runtime.h>
#include <hip/hip_fp16.h>

typedef unsigned int u32;

#define BATCH 256
#define TSTEPS 1024
#define HDIM 256
#define ODIM 32

// ---------------- workspace layout (bytes) ----------------
// blob: u32 [1024][144] per-(unit,slice) packed-f16 weights, shared by all batch blocks
// cvec/cvec0: f32 [256][3][256]
#define OFF_BLOB  0u
#define OFF_CVEC  589824u
#define OFF_CVEC0 1376256u

static __device__ __forceinline__ u32 packh2(float a, float b) {
  __half2 h = __floats2half2_rn(a, b);
  return *reinterpret_cast<u32*>(&h);
}

// 2 MACs from one packed-half2 weight word; f32 h and f32 accumulate.
// Pattern fmaf((float)half, f32, f32) should form v_fma_mix_f32.
static __device__ __forceinline__ float mac2(float acc, u32 w, float h0, float h1) {
  const __half2 hh = *reinterpret_cast<const __half2*>(&w);
  const float2 f = __half22float2(hh);
  acc = fmaf(f.x, h0, acc);
  acc = fmaf(f.y, h1, acc);
  return acc;
}

// ---------------------------------------------------------------------------
// k_pack: build per-thread weight blobs (folded matrices, f16).
//   tid = 4*j + s  (j = hidden unit, s = 64-elem h slice)
//   M_r = W_hh_r + W_ihy_r*W_out ; M_z likewise ; M_hn = W_hh_n ; M_xn = W_ihy_n*W_out
//   h-pair order is rotated by slice: chunk(p) = (p + 4*s) & 15  (bank-conflict fix;
//   the main kernel reads h at the rotated address and weights sequentially)
// grid 4 x 256
// ---------------------------------------------------------------------------
__global__ void k_pack(const float* __restrict__ W_ih, const float* __restrict__ W_hh,
                       const float* __restrict__ W_out, u32* __restrict__ blob) {
  const int tid = blockIdx.x * 256 + threadIdx.x;  // 0..1023
  const int j = tid >> 2, s = tid & 3;
  const int o = tid & 31, c = tid >> 5;
  u32* bb = blob + tid * 144;

  for (int p = 0; p < 16; ++p) {
    const int e0 = 64 * s + 4 * ((p + 4 * s) & 15);
    float vr[4], vz[4], vh[4], vx[4];
#pragma unroll
    for (int q = 0; q < 4; ++q) {
      vr[q] = W_hh[(j)       * HDIM + e0 + q];
      vz[q] = W_hh[(256 + j) * HDIM + e0 + q];
      vh[q] = W_hh[(512 + j) * HDIM + e0 + q];
      vx[q] = 0.f;
    }
#pragma unroll 8
    for (int u = 0; u < 32; ++u) {
      const float ar = W_ih[(j)       * 96 + 32 + u];
      const float az = W_ih[(256 + j) * 96 + 32 + u];
      const float an = W_ih[(512 + j) * 96 + 32 + u];
#pragma unroll
      for (int q = 0; q < 4; ++q) {
        const float wo = W_out[u * HDIM + e0 + q];
        vr[q] = fmaf(ar, wo, vr[q]);
        vz[q] = fmaf(az, wo, vz[q]);
        vx[q] = fmaf(an, wo, vx[q]);
      }
    }
    bb[      2 * p] = packh2(vr[0], vr[1]);  bb[      2 * p + 1] = packh2(vr[2], vr[3]);
    bb[32  + 2 * p] = packh2(vz[0], vz[1]);  bb[32  + 2 * p + 1] = packh2(vz[2], vz[3]);
    bb[64  + 2 * p] = packh2(vh[0], vh[1]);  bb[64  + 2 * p + 1] = packh2(vh[2], vh[3]);
    bb[96  + 2 * p] = packh2(vx[0], vx[1]);  bb[96  + 2 * p + 1] = packh2(vx[2], vx[3]);
  }
  // obs-weight fragments: gate g, obs elems 8s..8s+7
#pragma unroll
  for (int i = 0; i < 4; ++i) {
    bb[128 + i] = packh2(W_ih[(j)       * 96 + 8 * s + 2 * i], W_ih[(j)       * 96 + 8 * s + 2 * i + 1]);
    bb[132 + i] = packh2(W_ih[(256 + j) * 96 + 8 * s + 2 * i], W_ih[(256 + j) * 96 + 8 * s + 2 * i + 1]);
    bb[136 + i] = packh2(W_ih[(512 + j) * 96 + 8 * s + 2 * i], W_ih[(512 + j) * 96 + 8 * s + 2 * i + 1]);
  }
  // W_out fragment for the y phase: row o, h elems 8c..8c+7
#pragma unroll
  for (int i = 0; i < 4; ++i)
    bb[140 + i] = packh2(W_out[o * HDIM + 8 * c + 2 * i], W_out[o * HDIM + 8 * c + 2 * i + 1]);
}

// ---------------------------------------------------------------------------
// k_cvec: per-batch constants.
//   q=0 (r):  b_ih + b_hh + W_ihz.z + W_ihy.(b_out | init_y)
//   q=1 (z):  same
//   q=2 (xn): b_ih       + W_ihz.z + W_ihy.(b_out | init_y)   (b_hh_n kept separate)
// grid 256 x 256
// ---------------------------------------------------------------------------
__global__ void k_cvec(const float* __restrict__ W_ih, const float* __restrict__ b_ih,
                       const float* __restrict__ b_hh, const float* __restrict__ b_out,
                       const float* __restrict__ z_dyn, const float* __restrict__ init_y,
                       float* __restrict__ cvec, float* __restrict__ cvec0) {
  const int b = blockIdx.x, j = threadIdx.x;
  __shared__ float zs[32], bo[32], y0[32];
  if (j < 32) {
    zs[j] = z_dyn[b * 32 + j];
    bo[j] = b_out[j];
    y0[j] = init_y[b * 32 + j];
  }
  __syncthreads();
#pragma unroll
  for (int q = 0; q < 3; ++q) {
    const int g = q * 256 + j;
    const float base = b_ih[g] + ((q < 2) ? b_hh[g] : 0.f);
    float zd = 0.f, yd = 0.f, y0d = 0.f;
#pragma unroll 8
    for (int u = 0; u < 32; ++u) {
      const float wz = W_ih[g * 96 + 64 + u];
      const float wy = W_ih[g * 96 + 32 + u];
      zd  = fmaf(wz, zs[u], zd);
      yd  = fmaf(wy, bo[u], yd);
      y0d = fmaf(wy, y0[u], y0d);
    }
    cvec [(b * 3 + q) * 256 + j] = base + zd + yd;
    cvec0[(b * 3 + q) * 256 + j] = base + zd + y0d;
  }
}

// ---------------------------------------------------------------------------
// Main persistent GRU kernel. grid 256 (batch), block 1024.
// Quad (4 threads) per hidden unit; thread = (j = tid>>2, s = tid&3) covers
// h[64s..64s+63]. Weights in 144 VGPRs/thread (packed f16). h in LDS (f32).
// 2 barriers/step; y reduction pipelined one step behind.
// ---------------------------------------------------------------------------
__global__ __launch_bounds__(1024, 1) void k_gru(
    const float* __restrict__ obs, const u32* __restrict__ blob,
    const float* __restrict__ cvec, const float* __restrict__ cvec0,
    const float* __restrict__ b_hh, const float* __restrict__ b_out,
    float* __restrict__ out) {
  __shared__ float h_s[256];
  __shared__ float x_s[2][32];
  __shared__ float yp_s[2][16 * 32];

  const int b = blockIdx.x;
  const int tid = threadIdx.x;
  const int j = tid >> 2, s = tid & 3;
  const int o = tid & 31, c = tid >> 5;
  const int w = tid >> 6;
  const int lane = tid & 63;

  // ---- load per-thread weight blob (144 u32 = 36 uint4) ----
  u32 wb[144];
  {
    const uint4* src = reinterpret_cast<const uint4*>(blob + tid * 144);
#pragma unroll
    for (int i = 0; i < 36; ++i) {
      const uint4 v = src[i];
      wb[4 * i] = v.x; wb[4 * i + 1] = v.y; wb[4 * i + 2] = v.z; wb[4 * i + 3] = v.w;
    }
  }

  const float c_r1 = cvec [(b * 3 + 0) * 256 + j];
  const float c_z1 = cvec [(b * 3 + 1) * 256 + j];
  const float c_n1 = cvec [(b * 3 + 2) * 256 + j];
  const float c_r0 = cvec0[(b * 3 + 0) * 256 + j];
  const float c_z0 = cvec0[(b * 3 + 1) * 256 + j];
  const float c_n0 = cvec0[(b * 3 + 2) * 256 + j];
  const float chn  = b_hh[512 + j];
  const float bo   = b_out[o];

  // rotated h read addresses (byte offsets), computed once, statically indexed
  int hadr[16];
#pragma unroll
  for (int p = 0; p < 16; ++p) hadr[p] = (64 * s + 4 * ((p + 4 * s) & 15)) * 4;

  const float* obs_b = obs + (size_t)b * TSTEPS * 32;
  float* out_b = out + (size_t)b * TSTEPS * 32;

  float hreg = 0.f;
  if (tid < 256) h_s[tid] = 0.f;
  if (tid < 32) x_s[0][tid] = obs_b[tid];
  __syncthreads();

#pragma unroll 1
  for (int t = 0; t < TSTEPS; ++t) {
    const int cur = t & 1;
    // issue next-obs prefetch early (lands between barriers A and B)
    float pf = 0.f;
    if (tid < 32) pf = obs_b[(t < TSTEPS - 1 ? t + 1 : t) * 32 + tid];

    const float cr  = t ? c_r1 : c_r0;
    const float cz  = t ? c_z1 : c_z0;
    const float cxn = t ? c_n1 : c_n0;

    float aR = 0.f, aZ = 0.f, aXN = 0.f, aHN = 0.f;
#pragma unroll
    for (int p = 0; p < 16; ++p) {
      const float4 hv = *reinterpret_cast<const float4*>(
          reinterpret_cast<const char*>(h_s) + hadr[p]);
      aR  = mac2(aR,  wb[      2 * p], hv.x, hv.y);
      aR  = mac2(aR,  wb[      2 * p + 1], hv.z, hv.w);
      aZ  = mac2(aZ,  wb[32  + 2 * p], hv.x, hv.y);
      aZ  = mac2(aZ,  wb[32  + 2 * p + 1], hv.z, hv.w);
      aHN = mac2(aHN, wb[64  + 2 * p], hv.x, hv.y);
      aHN = mac2(aHN, wb[64  + 2 * p + 1], hv.z, hv.w);
      aXN = mac2(aXN, wb[96  + 2 * p], hv.x, hv.y);
      aXN = mac2(aXN, wb[96  + 2 * p + 1], hv.z, hv.w);
    }
#pragma unroll
    for (int i = 0; i < 2; ++i) {
      const float4 xv = *reinterpret_cast<const float4*>(&x_s[cur][8 * s + 4 * i]);
      aR  = mac2(aR,  wb[128 + 2 * i], xv.x, xv.y);
      aR  = mac2(aR,  wb[128 + 2 * i + 1], xv.z, xv.w);
      aZ  = mac2(aZ,  wb[132 + 2 * i], xv.x, xv.y);
      aZ  = mac2(aZ,  wb[132 + 2 * i + 1], xv.z, xv.w);
      aXN = mac2(aXN, wb[136 + 2 * i], xv.x, xv.y);
      aXN = mac2(aXN, wb[136 + 2 * i + 1], xv.z, xv.w);
    }

    // quad reduction (lanes 4j..4j+3)
#pragma unroll
    for (int m = 1; m <= 2; m <<= 1) {
      aR  += __shfl_xor(aR,  m, 64);
      aZ  += __shfl_xor(aZ,  m, 64);
      aHN += __shfl_xor(aHN, m, 64);
      aXN += __shfl_xor(aXN, m, 64);
    }

    const float r    = 1.f / (1.f + __expf(-(cr + aR)));
    const float zg   = 1.f / (1.f + __expf(-(cz + aZ)));
    const float pn   = cxn + aXN + r * (chn + aHN);
    const float n    = 1.f - 2.f / (1.f + __expf(2.f * pn));  // tanh
    const float hnew = fmaf(zg, hreg - n, n);
    hreg = hnew;

    __syncthreads();  // A: all reads of h_s / x_s[cur] done
    if (s == 0) h_s[j] = hnew;
    if (tid < 32) x_s[1 - cur][tid] = pf;
    if (t > 0 && tid < 32) {  // finalize y_{t-1} (partials written last step)
      float y = bo;
#pragma unroll
      for (int ww = 0; ww < 16; ++ww) y += yp_s[1 - cur][ww * 32 + tid];
      out_b[(t - 1) * 32 + tid] = y;
    }
    __syncthreads();  // B: new h visible

    // y partials for h_t (reduction deferred to next step)
    {
      const float4 h0 = *reinterpret_cast<const float4*>(&h_s[8 * c]);
      const float4 h1 = *reinterpret_cast<const float4*>(&h_s[8 * c + 4]);
      float yv = 0.f;
      yv = mac2(yv, wb[140], h0.x, h0.y);
      yv = mac2(yv, wb[141], h0.z, h0.w);
      yv = mac2(yv, wb[142], h1.x, h1.y);
      yv = mac2(yv, wb[143], h1.z, h1.w);
      yv += __shfl_xor(yv, 32, 64);
      if (lane < 32) yp_s[cur][w * 32 + o] = yv;
    }
  }

  __syncthreads();
  if (tid < 32) {  // flush y_1023
    float y = bo;
#pragma unroll
    for (int ww = 0; ww < 16; ++ww) y += yp_s[1][ww * 32 + tid];
    out_b[(TSTEPS - 1) * 32 + tid] = y;
  }
}

// ---------------------------------------------------------------------------
extern "C" void kernel_launch(void* const* d_in, const int* in_sizes, int n_in,
                              void* d_out, int out_size, void* d_ws, size_t ws_size,
                              hipStream_t stream) {
  (void)in_sizes; (void)n_in; (void)out_size; (void)ws_size;
  const float* init_y  = (const float*)d_in[0];
  const float* obs_seq = (const float*)d_in[1];
  const float* z_dyn   = (const float*)d_in[2];
  const float* W_ih    = (const float*)d_in[3];
  const float* W_hh    = (const float*)d_in[4];
  const float* b_ih    = (const float*)d_in[5];
  const float* b_hh    = (const float*)d_in[6];
  const float* W_out   = (const float*)d_in[7];
  const float* b_out   = (const float*)d_in[8];
  float* out = (float*)d_out;

  char* ws = (char*)d_ws;
  u32*   blob  = (u32*)(ws + OFF_BLOB);
  float* cvec  = (float*)(ws + OFF_CVEC);
  float* cvec0 = (float*)(ws + OFF_CVEC0);

  k_pack<<<4, 256, 0, stream>>>(W_ih, W_hh, W_out, blob);
  k_cvec<<<256, 256, 0, stream>>>(W_ih, b_ih, b_hh, b_out, z_dyn, init_y, cvec, cvec0);
  k_gru<<<BATCH, 1024, 0, stream>>>(obs_seq, blob, cvec, cvec0, b_hh, b_out, out);
}